// Round 1
// baseline (723.658 us; speedup 1.0000x reference)
//
#include <hip/hip_runtime.h>
#include <hip/hip_bf16.h>

#define NEG 0.2f

__device__ __forceinline__ float lrelu(float x){ return x > 0.f ? x : NEG * x; }
__device__ __forceinline__ float elu_f(float x){ return x > 0.f ? x : expm1f(x); }

// ---------------- CSR build ----------------
__global__ void k_count(const int* __restrict__ dst, int E, int* deg){
  int e = blockIdx.x * blockDim.x + threadIdx.x;
  if (e < E) atomicAdd(&deg[dst[e]], 1);
}

// block = 256 threads, 1024 elements/block; value = deg[i]+1 (self-loop)
__global__ void k_scan1(const int* __restrict__ deg, int* row_ptr, int* partials, int N){
  __shared__ int sd[256];
  int t = threadIdx.x;
  int base = blockIdx.x * 1024 + t * 4;
  int v[4]; int s = 0;
  #pragma unroll
  for (int j = 0; j < 4; j++){ int i = base + j; v[j] = (i < N) ? (deg[i] + 1) : 0; s += v[j]; }
  sd[t] = s; __syncthreads();
  for (int off = 1; off < 256; off <<= 1){
    int x = (t >= off) ? sd[t - off] : 0;
    __syncthreads(); sd[t] += x; __syncthreads();
  }
  int pre = (t > 0) ? sd[t - 1] : 0;
  #pragma unroll
  for (int j = 0; j < 4; j++){ int i = base + j; if (i < N) row_ptr[i] = pre; pre += v[j]; }
  if (t == 255) partials[blockIdx.x] = sd[255];
}

__global__ void k_scan2(int* partials, int NB){
  __shared__ int sd[128];
  int t = threadIdx.x;
  int v = (t < NB) ? partials[t] : 0;
  sd[t] = v; __syncthreads();
  for (int off = 1; off < 128; off <<= 1){
    int x = (t >= off) ? sd[t - off] : 0;
    __syncthreads(); sd[t] += x; __syncthreads();
  }
  if (t < NB) partials[t] = sd[t] - v;   // exclusive
}

__global__ void k_scan3(int* row_ptr, int* cursor, const int* __restrict__ partials, int N, int total){
  int i = blockIdx.x * blockDim.x + threadIdx.x;
  if (i < N){ int r = row_ptr[i] + partials[i >> 10]; row_ptr[i] = r; cursor[i] = r; }
  if (i == 0) row_ptr[N] = total;
}

__global__ void k_scatter(const int* __restrict__ src, const int* __restrict__ dst,
                          int E, int N, int* cursor, int* __restrict__ csr_src){
  int e = blockIdx.x * blockDim.x + threadIdx.x;
  int tot = E + N;
  if (e >= tot) return;
  int s, d;
  if (e < E){ s = src[e]; d = dst[e]; } else { s = e - E; d = s; }
  int pos = atomicAdd(&cursor[d], 1);
  csr_src[pos] = s;
}

// ---------------- GEMM1: x[N,128] @ W[128,128] -> h[N,128], + s_src1/s_dst1[N,4] ----------------
__global__ __launch_bounds__(256) void k_gemm1(
    const float* __restrict__ x, const float* __restrict__ W,
    const float* __restrict__ a_src, const float* __restrict__ a_dst,
    float* __restrict__ h, float* __restrict__ s_src, float* __restrict__ s_dst, int N){
  __shared__ __align__(16) float Wl[128 * 128];
  __shared__ __align__(16) float Xl[32 * 132];
  int t = threadIdx.x;
  int rb = blockIdx.x * 32;

  const float4* Wg4 = (const float4*)W;
  float4* Wl4 = (float4*)Wl;
  #pragma unroll
  for (int j = 0; j < 16; j++) Wl4[j * 256 + t] = Wg4[j * 256 + t];

  #pragma unroll
  for (int j = 0; j < 4; j++){
    int fi = j * 256 + t;           // float4 index within 32x128 tile
    int row = fi >> 5; int kc = (fi & 31) * 4;
    float4 v = make_float4(0.f, 0.f, 0.f, 0.f);
    if (rb + row < N) v = *(const float4*)&x[(size_t)(rb + row) * 128 + kc];
    *(float4*)&Xl[row * 132 + kc] = v;
  }
  __syncthreads();

  int cg = t & 15, rg = t >> 4;
  int c0 = cg * 8, r0 = rg * 2;
  float acc[2][8];
  #pragma unroll
  for (int i = 0; i < 2; i++)
    #pragma unroll
    for (int j = 0; j < 8; j++) acc[i][j] = 0.f;

  #pragma unroll 8
  for (int k = 0; k < 128; k++){
    float a0 = Xl[r0 * 132 + k];
    float a1 = Xl[(r0 + 1) * 132 + k];
    float4 b0 = *(float4*)&Wl[k * 128 + c0];
    float4 b1 = *(float4*)&Wl[k * 128 + c0 + 4];
    float bb[8] = {b0.x, b0.y, b0.z, b0.w, b1.x, b1.y, b1.z, b1.w};
    #pragma unroll
    for (int j = 0; j < 8; j++){ acc[0][j] += a0 * bb[j]; acc[1][j] += a1 * bb[j]; }
  }

  int hd = c0 >> 5;
  float as[8], ad[8];
  #pragma unroll
  for (int j = 0; j < 8; j++){ as[j] = a_src[c0 + j]; ad[j] = a_dst[c0 + j]; }
  #pragma unroll
  for (int i = 0; i < 2; i++){
    int row = rb + r0 + i;
    if (row < N){
      *(float4*)&h[(size_t)row * 128 + c0]     = make_float4(acc[i][0], acc[i][1], acc[i][2], acc[i][3]);
      *(float4*)&h[(size_t)row * 128 + c0 + 4] = make_float4(acc[i][4], acc[i][5], acc[i][6], acc[i][7]);
    }
    float ps = 0.f, pd = 0.f;
    #pragma unroll
    for (int j = 0; j < 8; j++){ ps += acc[i][j] * as[j]; pd += acc[i][j] * ad[j]; }
    ps += __shfl_xor(ps, 1, 4); ps += __shfl_xor(ps, 2, 4);
    pd += __shfl_xor(pd, 1, 4); pd += __shfl_xor(pd, 2, 4);
    if ((t & 3) == 0 && row < N){ s_src[row * 4 + hd] = ps; s_dst[row * 4 + hd] = pd; }
  }
}

// ---------------- agg1: gather-side softmax-aggregate, 1 block per dst node ----------------
__global__ __launch_bounds__(128) void k_agg1(
    const int* __restrict__ row_ptr, const int* __restrict__ csr_src,
    const float* __restrict__ s_src, const float* __restrict__ s_dst,
    const float* __restrict__ h, float* __restrict__ out1, int N){
  int n = blockIdx.x;
  int c = threadIdx.x;            // 0..127
  int hd = c >> 5;
  float sdv = s_dst[n * 4 + hd];
  int beg = row_ptr[n], end = row_ptr[n + 1];
  float acc = 0.f, sw = 0.f;
  for (int e = beg; e < end; e++){
    int s = csr_src[e];
    float w = __expf(lrelu(s_src[s * 4 + hd] + sdv));
    acc += w * h[(size_t)s * 128 + c];
    sw += w;
  }
  out1[(size_t)n * 128 + c] = acc / (sw + 1e-16f);
}

// ---------------- GEMM2: elu(out1+b1)[N,128] @ W2[128,32] -> h2[N,32], + s_src2/s_dst2[N] ----------------
__global__ __launch_bounds__(256) void k_gemm2(
    const float* __restrict__ out1, const float* __restrict__ b1,
    const float* __restrict__ W2,
    const float* __restrict__ a_src, const float* __restrict__ a_dst,
    float* __restrict__ h2, float* __restrict__ s_src2, float* __restrict__ s_dst2, int N){
  __shared__ __align__(16) float Wl[128 * 32];
  __shared__ __align__(16) float Xl[64 * 132];
  int t = threadIdx.x;
  int rb = blockIdx.x * 64;

  const float4* Wg4 = (const float4*)W2;
  float4* Wl4 = (float4*)Wl;
  #pragma unroll
  for (int j = 0; j < 4; j++) Wl4[j * 256 + t] = Wg4[j * 256 + t];

  #pragma unroll
  for (int j = 0; j < 8; j++){
    int fi = j * 256 + t;           // float4 index within 64x128 tile
    int row = fi >> 5; int kc = (fi & 31) * 4;
    float4 v = make_float4(0.f, 0.f, 0.f, 0.f);
    if (rb + row < N){
      float4 xv = *(const float4*)&out1[(size_t)(rb + row) * 128 + kc];
      float4 bv = *(const float4*)&b1[kc];
      v.x = elu_f(xv.x + bv.x); v.y = elu_f(xv.y + bv.y);
      v.z = elu_f(xv.z + bv.z); v.w = elu_f(xv.w + bv.w);
    }
    *(float4*)&Xl[row * 132 + kc] = v;
  }
  __syncthreads();

  int cg = t & 7, rg = t >> 3;
  int c0 = cg * 4, r0 = rg * 2;
  float acc[2][4];
  #pragma unroll
  for (int i = 0; i < 2; i++)
    #pragma unroll
    for (int j = 0; j < 4; j++) acc[i][j] = 0.f;

  #pragma unroll 8
  for (int k = 0; k < 128; k++){
    float a0 = Xl[r0 * 132 + k];
    float a1 = Xl[(r0 + 1) * 132 + k];
    float4 b = *(float4*)&Wl[k * 32 + c0];
    acc[0][0] += a0 * b.x; acc[0][1] += a0 * b.y; acc[0][2] += a0 * b.z; acc[0][3] += a0 * b.w;
    acc[1][0] += a1 * b.x; acc[1][1] += a1 * b.y; acc[1][2] += a1 * b.z; acc[1][3] += a1 * b.w;
  }

  float as[4], ad[4];
  #pragma unroll
  for (int j = 0; j < 4; j++){ as[j] = a_src[c0 + j]; ad[j] = a_dst[c0 + j]; }
  #pragma unroll
  for (int i = 0; i < 2; i++){
    int row = rb + r0 + i;
    if (row < N)
      *(float4*)&h2[(size_t)row * 32 + c0] = make_float4(acc[i][0], acc[i][1], acc[i][2], acc[i][3]);
    float ps = 0.f, pd = 0.f;
    #pragma unroll
    for (int j = 0; j < 4; j++){ ps += acc[i][j] * as[j]; pd += acc[i][j] * ad[j]; }
    ps += __shfl_xor(ps, 1, 8); ps += __shfl_xor(ps, 2, 8); ps += __shfl_xor(ps, 4, 8);
    pd += __shfl_xor(pd, 1, 8); pd += __shfl_xor(pd, 2, 8); pd += __shfl_xor(pd, 4, 8);
    if ((t & 7) == 0 && row < N){ s_src2[row] = ps; s_dst2[row] = pd; }
  }
}

// ---------------- agg2: layer-2 aggregate, 4 nodes/block (32 ch each), writes final out ----------------
__global__ __launch_bounds__(128) void k_agg2(
    const int* __restrict__ row_ptr, const int* __restrict__ csr_src,
    const float* __restrict__ s_src2, const float* __restrict__ s_dst2,
    const float* __restrict__ h2, const float* __restrict__ b2,
    float* __restrict__ out, int N){
  int n = blockIdx.x * 4 + (threadIdx.x >> 5);
  if (n >= N) return;
  int c = threadIdx.x & 31;
  float sdv = s_dst2[n];
  int beg = row_ptr[n], end = row_ptr[n + 1];
  float acc = 0.f, sw = 0.f;
  for (int e = beg; e < end; e++){
    int s = csr_src[e];
    float w = __expf(lrelu(s_src2[s] + sdv));
    acc += w * h2[(size_t)s * 32 + c];
    sw += w;
  }
  out[(size_t)n * 32 + c] = acc / (sw + 1e-16f) + b2[c];
}

extern "C" void kernel_launch(void* const* d_in, const int* in_sizes, int n_in,
                              void* d_out, int out_size, void* d_ws, size_t ws_size,
                              hipStream_t stream) {
  const float* x      = (const float*)d_in[0];
  const int*   ei     = (const int*)  d_in[1];
  const float* W1     = (const float*)d_in[2];
  const float* a_src1 = (const float*)d_in[3];
  const float* a_dst1 = (const float*)d_in[4];
  const float* b1     = (const float*)d_in[5];
  const float* W2     = (const float*)d_in[6];
  const float* a_src2 = (const float*)d_in[7];
  const float* a_dst2 = (const float*)d_in[8];
  const float* b2     = (const float*)d_in[9];
  float* out = (float*)d_out;

  int N = in_sizes[0] / 128;
  int E = in_sizes[1] / 2;
  const int* srcp = ei;
  const int* dstp = ei + E;
  int total = E + N;

  char* p = (char*)d_ws;
  auto alloc = [&](size_t bytes) -> void* {
    void* r = (void*)p; p += (bytes + 255) & ~(size_t)255; return r;
  };
  float* h    = (float*)alloc((size_t)N * 128 * 4);
  float* out1 = (float*)alloc((size_t)N * 128 * 4);
  float* h2   = (float*)alloc((size_t)N * 32 * 4);
  float* ss1  = (float*)alloc((size_t)N * 4 * 4);
  float* sd1  = (float*)alloc((size_t)N * 4 * 4);
  float* ss2  = (float*)alloc((size_t)N * 4);
  float* sd2  = (float*)alloc((size_t)N * 4);
  int* deg    = (int*)alloc((size_t)N * 4);
  int* rowp   = (int*)alloc((size_t)(N + 1) * 4);
  int* cursor = (int*)alloc((size_t)N * 4);
  int* csr    = (int*)alloc((size_t)total * 4);
  int* parts  = (int*)alloc(256 * 4);
  (void)ws_size; (void)n_in; (void)out_size;

  hipMemsetAsync(deg, 0, (size_t)N * 4, stream);
  k_count<<<(E + 255) / 256, 256, 0, stream>>>(dstp, E, deg);
  int NB = (N + 1023) / 1024;
  k_scan1<<<NB, 256, 0, stream>>>(deg, rowp, parts, N);
  k_scan2<<<1, 128, 0, stream>>>(parts, NB);
  k_scan3<<<(N + 255) / 256, 256, 0, stream>>>(rowp, cursor, parts, N, total);
  k_scatter<<<(total + 255) / 256, 256, 0, stream>>>(srcp, dstp, E, N, cursor, csr);

  k_gemm1<<<(N + 31) / 32, 256, 0, stream>>>(x, W1, a_src1, a_dst1, h, ss1, sd1, N);
  k_agg1<<<N, 128, 0, stream>>>(rowp, csr, ss1, sd1, h, out1, N);
  k_gemm2<<<(N + 63) / 64, 256, 0, stream>>>(out1, b1, W2, a_src2, a_dst2, h2, ss2, sd2, N);
  k_agg2<<<(N + 3) / 4, 128, 0, stream>>>(rowp, csr, ss2, sd2, h2, b2, out, N);
}